// Round 3
// baseline (682.398 us; speedup 1.0000x reference)
//
#include <hip/hip_runtime.h>

#define NNODES 100000
#define NEDGES 1600000
#define DDIM   128

typedef __attribute__((ext_vector_type(8))) short short8;
typedef __attribute__((ext_vector_type(4))) float f32x4;

// f32 -> bf16 round-to-nearest-even (bit trick; NaN irrelevant here)
__device__ __forceinline__ unsigned short f2bf(float f) {
    unsigned u = __float_as_uint(f);
    u += 0x7FFFu + ((u >> 16) & 1u);
    return (unsigned short)(u >> 16);
}

// ---------------- CSR build ----------------

__global__ void sage_hist(const int* __restrict__ dst, int* __restrict__ deg) {
    int i = blockIdx.x * blockDim.x + threadIdx.x;
    if (i < NEDGES) atomicAdd(&deg[dst[i]], 1);
}

// single-block exclusive scan of deg[0..N) -> rowptr[0..N]
__global__ void __launch_bounds__(1024) sage_scan(const int* __restrict__ deg,
                                                  int* __restrict__ rowptr) {
    __shared__ int sums[1024];
    const int t = threadIdx.x;
    const int CH = (NNODES + 1023) / 1024;  // 98
    int b = t * CH;
    int e = b + CH; if (e > NNODES) e = NNODES;
    if (b > NNODES) b = NNODES;
    int s = 0;
    for (int i = b; i < e; ++i) s += deg[i];
    sums[t] = s;
    __syncthreads();
    // Hillis-Steele inclusive scan
    for (int off = 1; off < 1024; off <<= 1) {
        int v = (t >= off) ? sums[t - off] : 0;
        __syncthreads();
        sums[t] += v;
        __syncthreads();
    }
    int run = (t == 0) ? 0 : sums[t - 1];
    for (int i = b; i < e; ++i) { rowptr[i] = run; run += deg[i]; }
    if (t == 1023) rowptr[NNODES] = sums[1023];
}

__global__ void sage_scatter(const int* __restrict__ src, const int* __restrict__ dst,
                             const int* __restrict__ rowptr, int* __restrict__ fill,
                             int* __restrict__ sorted) {
    int i = blockIdx.x * blockDim.x + threadIdx.x;
    if (i < NEDGES) {
        int d = dst[i];
        int pos = rowptr[d] + atomicAdd(&fill[d], 1);
        sorted[pos] = src[i];
    }
}

// ---------------- dtype prep ----------------

// f32 -> bf16, 4 elems/thread
__global__ void sage_cvt(const float* __restrict__ in, unsigned short* __restrict__ out, int n) {
    int i = (blockIdx.x * blockDim.x + threadIdx.x) * 4;
    if (i < n) {
        float4 v = *(const float4*)&in[i];
        uint2 o;
        o.x = (unsigned)f2bf(v.x) | ((unsigned)f2bf(v.y) << 16);
        o.y = (unsigned)f2bf(v.z) | ((unsigned)f2bf(v.w) << 16);
        *(uint2*)&out[i] = o;
    }
}

// Wcat[j][k] = (k<128 ? Wl[j][k] : Wr[j][k-128]) as bf16;  [128][256]
__global__ void sage_wprep(const float* __restrict__ Wl, const float* __restrict__ Wr,
                           unsigned short* __restrict__ Wcat) {
    int idx = blockIdx.x * blockDim.x + threadIdx.x;  // 0..32767
    int j = idx >> 8, k = idx & 255;
    float v = (k < 128) ? Wl[j * 128 + k] : Wr[j * 128 + (k - 128)];
    Wcat[idx] = f2bf(v);
}

// ---------------- aggregation (one wave per node) ----------------
// in: [N][128] bf16.  ag: [N][128] bf16 = mean over neighbors (0 if none)

__global__ void __launch_bounds__(256) sage_aggr(const unsigned short* __restrict__ in,
                                                 const int* __restrict__ rowptr,
                                                 const int* __restrict__ srcs,
                                                 unsigned short* __restrict__ ag) {
    int node = blockIdx.x * 4 + (threadIdx.x >> 6);
    if (node >= NNODES) return;
    int lane = threadIdx.x & 63;
    int beg = rowptr[node], end = rowptr[node + 1];
    const unsigned* inu = (const unsigned*)in;   // 64 uints per row
    float s0 = 0.f, s1 = 0.f;
    int i = beg;
    for (; i + 4 <= end; i += 4) {
        int n0 = srcs[i], n1 = srcs[i + 1], n2 = srcs[i + 2], n3 = srcs[i + 3];
        unsigned v0 = inu[n0 * 64 + lane];
        unsigned v1 = inu[n1 * 64 + lane];
        unsigned v2 = inu[n2 * 64 + lane];
        unsigned v3 = inu[n3 * 64 + lane];
        s0 += __uint_as_float(v0 << 16);
        s1 += __uint_as_float(v0 & 0xFFFF0000u);
        s0 += __uint_as_float(v1 << 16);
        s1 += __uint_as_float(v1 & 0xFFFF0000u);
        s0 += __uint_as_float(v2 << 16);
        s1 += __uint_as_float(v2 & 0xFFFF0000u);
        s0 += __uint_as_float(v3 << 16);
        s1 += __uint_as_float(v3 & 0xFFFF0000u);
    }
    for (; i < end; ++i) {
        unsigned v = inu[srcs[i] * 64 + lane];
        s0 += __uint_as_float(v << 16);
        s1 += __uint_as_float(v & 0xFFFF0000u);
    }
    int cnt = end - beg;
    float inv = (cnt > 0) ? 1.0f / (float)cnt : 0.0f;
    s0 *= inv; s1 *= inv;
    unsigned* agu = (unsigned*)ag;               // 64 uints per row
    agu[node * 64 + lane] = (unsigned)f2bf(s0) | ((unsigned)f2bf(s1) << 16);
}

// ---------------- GEMM: out[i][j] = sum_k Acat[i][k]*W[j][k] + bias[j] ----------------
// Acat = [A0 | A1] (two [M][128] bf16 buffers: aggr and self).
// W: [128][256] bf16. Tile 128x128, K=256 in 4 steps of 64. LDS 32 KiB static.
// EPI 0: relu + bf16 store (layer 1).  EPI 1: f32 store (layer 2).

template <int EPI>
__global__ void __launch_bounds__(256) sage_gemm(const unsigned short* __restrict__ A0,
                                                 const unsigned short* __restrict__ A1,
                                                 const unsigned short* __restrict__ W,
                                                 const float* __restrict__ bias,
                                                 void* __restrict__ outp) {
    __shared__ unsigned short As[128 * 64];
    __shared__ unsigned short Bs[128 * 64];
    const int tid = threadIdx.x;
    const int bm = blockIdx.x * 128;

    f32x4 acc[4][4];
    const f32x4 zero = {0.f, 0.f, 0.f, 0.f};
    for (int m = 0; m < 4; ++m)
        for (int n = 0; n < 4; ++n) acc[m][n] = zero;

    const int lane = tid & 63, wid = tid >> 6;
    const int wr = wid >> 1, wc = wid & 1;
    const int l16 = lane & 15, lhi = lane >> 4;

    for (int kt = 0; kt < 256; kt += 64) {
        const unsigned short* Asrc = (kt < 128) ? A0 : A1;
        const int kofs = kt & 127;
        __syncthreads();  // protect LDS reuse from previous iteration
        #pragma unroll
        for (int it = 0; it < 4; ++it) {
            int idx = it * 2048 + tid * 8;
            int r = idx >> 6, k = idx & 63;
            int row = bm + r; if (row >= NNODES) row = NNODES - 1;
            *(int4*)&As[idx] = *(const int4*)&Asrc[row * 128 + kofs + k];
            *(int4*)&Bs[idx] = *(const int4*)&W[r * 256 + kt + k];
        }
        __syncthreads();
        #pragma unroll
        for (int kk = 0; kk < 64; kk += 32) {
            short8 af[4], bf[4];
            #pragma unroll
            for (int m = 0; m < 4; ++m)
                af[m] = *(const short8*)&As[(wr * 64 + m * 16 + l16) * 64 + kk + lhi * 8];
            #pragma unroll
            for (int n = 0; n < 4; ++n)
                bf[n] = *(const short8*)&Bs[(wc * 64 + n * 16 + l16) * 64 + kk + lhi * 8];
            #pragma unroll
            for (int m = 0; m < 4; ++m)
                #pragma unroll
                for (int n = 0; n < 4; ++n)
                    acc[m][n] = __builtin_amdgcn_mfma_f32_16x16x32_bf16(af[m], bf[n], acc[m][n], 0, 0, 0);
        }
    }

    for (int n = 0; n < 4; ++n) {
        int col = wc * 64 + n * 16 + l16;
        float bv = bias[col];
        for (int m = 0; m < 4; ++m) {
            int row0 = bm + wr * 64 + m * 16 + lhi * 4;
            #pragma unroll
            for (int v = 0; v < 4; ++v) {
                int row = row0 + v;
                if (row < NNODES) {
                    float val = acc[m][n][v] + bv;
                    if (EPI == 0) {
                        val = fmaxf(val, 0.0f);
                        ((unsigned short*)outp)[row * 128 + col] = f2bf(val);
                    } else {
                        ((float*)outp)[row * 128 + col] = val;
                    }
                }
            }
        }
    }
}

// ---------------- row L2 normalize in place (one wave per row) ----------------

__global__ void __launch_bounds__(256) sage_norm(float* __restrict__ out) {
    int node = blockIdx.x * 4 + (threadIdx.x >> 6);
    if (node >= NNODES) return;
    int lane = threadIdx.x & 63;
    float2 v = *(float2*)&out[node * 128 + lane * 2];
    float s = v.x * v.x + v.y * v.y;
    for (int off = 32; off; off >>= 1) s += __shfl_xor(s, off);
    float scale = 1.0f / fmaxf(sqrtf(s), 1e-12f);
    v.x *= scale; v.y *= scale;
    *(float2*)&out[node * 128 + lane * 2] = v;
}

// ---------------- launch ----------------

extern "C" void kernel_launch(void* const* d_in, const int* in_sizes, int n_in,
                              void* d_out, int out_size, void* d_ws, size_t ws_size,
                              hipStream_t stream) {
    const float* x   = (const float*)d_in[0];
    const int* ei    = (const int*)d_in[1];
    const float* W1l = (const float*)d_in[2];
    const float* b1  = (const float*)d_in[3];
    const float* W1r = (const float*)d_in[4];
    const float* W2l = (const float*)d_in[5];
    const float* b2  = (const float*)d_in[6];
    const float* W2r = (const float*)d_in[7];
    const int* srcp = ei;
    const int* dstp = ei + NEDGES;

    char* ws = (char*)d_ws;
    size_t off = 0;
    auto alloc = [&](size_t bytes) -> void* {
        void* p = ws + off;
        off += (bytes + 255) & ~(size_t)255;
        return p;
    };
    int* deg    = (int*)alloc((size_t)NNODES * 4);          // reused as fill
    int* rowptr = (int*)alloc((size_t)(NNODES + 1) * 4);
    int* sorted = (int*)alloc((size_t)NEDGES * 4);
    unsigned short* xb = (unsigned short*)alloc((size_t)NNODES * DDIM * 2);  // also hb (aliased in time)
    unsigned short* ag = (unsigned short*)alloc((size_t)NNODES * DDIM * 2);
    unsigned short* wc1 = (unsigned short*)alloc(128 * 256 * 2);
    unsigned short* wc2 = (unsigned short*)alloc(128 * 256 * 2);
    unsigned short* hb = xb;  // layer-1 output overwrites xb in place (per-block row ownership)

    // CSR build
    hipMemsetAsync(deg, 0, (size_t)NNODES * 4, stream);
    sage_hist<<<(NEDGES + 255) / 256, 256, 0, stream>>>(dstp, deg);
    sage_scan<<<1, 1024, 0, stream>>>(deg, rowptr);
    hipMemsetAsync(deg, 0, (size_t)NNODES * 4, stream);
    sage_scatter<<<(NEDGES + 255) / 256, 256, 0, stream>>>(srcp, dstp, rowptr, deg, sorted);

    // dtype prep
    sage_cvt<<<(NNODES * DDIM / 4 + 255) / 256, 256, 0, stream>>>(x, xb, NNODES * DDIM);
    sage_wprep<<<128, 256, 0, stream>>>(W1l, W1r, wc1);
    sage_wprep<<<128, 256, 0, stream>>>(W2l, W2r, wc2);

    const int aggr_grid = (NNODES + 3) / 4;
    const int gemm_grid = (NNODES + 127) / 128;

    // layer 1: h = relu(aggr@W1l.T + b1 + x@W1r.T)   (bf16, in place over xb)
    sage_aggr<<<aggr_grid, 256, 0, stream>>>(xb, rowptr, sorted, ag);
    sage_gemm<0><<<gemm_grid, 256, 0, stream>>>(ag, xb, wc1, b1, (void*)hb);
    // layer 2: out = aggr@W2l.T + b2 + h@W2r.T       (f32)
    sage_aggr<<<aggr_grid, 256, 0, stream>>>(hb, rowptr, sorted, ag);
    sage_gemm<1><<<gemm_grid, 256, 0, stream>>>(ag, hb, wc2, b2, d_out);
    // normalize rows
    sage_norm<<<aggr_grid, 256, 0, stream>>>((float*)d_out);
}

// Round 4
// 531.436 us; speedup vs baseline: 1.2841x; 1.2841x over previous
//
#include <hip/hip_runtime.h>

#define NNODES 100000
#define NEDGES 1600000
#define DDIM   128
#define SCAN_NB ((NNODES + 1023) / 1024)   // 98

typedef __attribute__((ext_vector_type(8))) short short8;
typedef __attribute__((ext_vector_type(4))) float f32x4;

// f32 -> bf16 round-to-nearest-even (bit trick; NaN irrelevant here)
__device__ __forceinline__ unsigned short f2bf(float f) {
    unsigned u = __float_as_uint(f);
    u += 0x7FFFu + ((u >> 16) & 1u);
    return (unsigned short)(u >> 16);
}

// ---------------- CSR build ----------------

__global__ void sage_hist(const int* __restrict__ dst, int* __restrict__ deg) {
    int i = blockIdx.x * blockDim.x + threadIdx.x;
    if (i < NEDGES) atomicAdd(&deg[dst[i]], 1);
}

// Phase 1: per-block sums over 1024-elem chunks (256 thr x 4)
__global__ void __launch_bounds__(256) sage_scan1(const int* __restrict__ deg,
                                                  int* __restrict__ bsum) {
    int idx0 = blockIdx.x * 1024 + threadIdx.x * 4;
    int local = 0;
    if (idx0 < NNODES) {   // NNODES % 4 == 0 -> full int4 in bounds
        int4 v = *(const int4*)&deg[idx0];
        local = v.x + v.y + v.z + v.w;
    }
    // reduce across 256 threads
    int lane = threadIdx.x & 63, w = threadIdx.x >> 6;
    for (int off = 32; off; off >>= 1) local += __shfl_down(local, off);
    __shared__ int ws[4];
    if (lane == 0) ws[w] = local;
    __syncthreads();
    if (threadIdx.x == 0) bsum[blockIdx.x] = ws[0] + ws[1] + ws[2] + ws[3];
}

// Phase 2: scan the 98 block sums (one small block)
__global__ void __launch_bounds__(128) sage_scan2(const int* __restrict__ bsum,
                                                  int* __restrict__ bofs,
                                                  int* __restrict__ rowptr) {
    __shared__ int sm[128];
    int t = threadIdx.x;
    int v = (t < SCAN_NB) ? bsum[t] : 0;
    sm[t] = v;
    __syncthreads();
    for (int off = 1; off < 128; off <<= 1) {
        int u = (t >= off) ? sm[t - off] : 0;
        __syncthreads();
        sm[t] += u;
        __syncthreads();
    }
    if (t < SCAN_NB) bofs[t] = sm[t] - v;            // exclusive block offset
    if (t == SCAN_NB - 1) rowptr[NNODES] = sm[t];    // total edge count
}

// Phase 3: block-local exclusive scan + block offset -> rowptr
__global__ void __launch_bounds__(256) sage_scan3(const int* __restrict__ deg,
                                                  const int* __restrict__ bofs,
                                                  int* __restrict__ rowptr) {
    int idx0 = blockIdx.x * 1024 + threadIdx.x * 4;
    int4 v = {0, 0, 0, 0};
    if (idx0 < NNODES) v = *(const int4*)&deg[idx0];
    int local = v.x + v.y + v.z + v.w;
    int lane = threadIdx.x & 63, w = threadIdx.x >> 6;
    // inclusive wave scan
    int sc = local;
    for (int off = 1; off < 64; off <<= 1) {
        int u = __shfl_up(sc, off);
        if (lane >= off) sc += u;
    }
    __shared__ int ws[4];
    if (lane == 63) ws[w] = sc;
    __syncthreads();
    int wofs = 0;
    for (int i = 0; i < 4; ++i) if (i < w) wofs += ws[i];
    int excl = bofs[blockIdx.x] + wofs + sc - local;  // exclusive prefix at idx0
    if (idx0 < NNODES) {
        rowptr[idx0]     = excl;
        rowptr[idx0 + 1] = excl + v.x;
        rowptr[idx0 + 2] = excl + v.x + v.y;
        rowptr[idx0 + 3] = excl + v.x + v.y + v.z;
    }
}

__global__ void sage_scatter(const int* __restrict__ src, const int* __restrict__ dst,
                             const int* __restrict__ rowptr, int* __restrict__ fill,
                             int* __restrict__ sorted) {
    int i = blockIdx.x * blockDim.x + threadIdx.x;
    if (i < NEDGES) {
        int d = dst[i];
        int pos = rowptr[d] + atomicAdd(&fill[d], 1);
        sorted[pos] = src[i];
    }
}

// ---------------- dtype prep ----------------

// f32 -> bf16, 4 elems/thread
__global__ void sage_cvt(const float* __restrict__ in, unsigned short* __restrict__ out, int n) {
    int i = (blockIdx.x * blockDim.x + threadIdx.x) * 4;
    if (i < n) {
        float4 v = *(const float4*)&in[i];
        uint2 o;
        o.x = (unsigned)f2bf(v.x) | ((unsigned)f2bf(v.y) << 16);
        o.y = (unsigned)f2bf(v.z) | ((unsigned)f2bf(v.w) << 16);
        *(uint2*)&out[i] = o;
    }
}

// Wcat[j][k] = (k<128 ? Wl[j][k] : Wr[j][k-128]) as bf16;  [128][256]
__global__ void sage_wprep(const float* __restrict__ Wl, const float* __restrict__ Wr,
                           unsigned short* __restrict__ Wcat) {
    int idx = blockIdx.x * blockDim.x + threadIdx.x;  // 0..32767
    int j = idx >> 8, k = idx & 255;
    float v = (k < 128) ? Wl[j * 128 + k] : Wr[j * 128 + (k - 128)];
    Wcat[idx] = f2bf(v);
}

// ---------------- aggregation (one wave per node) ----------------
// in: [N][128] bf16.  ag: [N][128] bf16 = mean over neighbors (0 if none)

__global__ void __launch_bounds__(256) sage_aggr(const unsigned short* __restrict__ in,
                                                 const int* __restrict__ rowptr,
                                                 const int* __restrict__ srcs,
                                                 unsigned short* __restrict__ ag) {
    int node = blockIdx.x * 4 + (threadIdx.x >> 6);
    if (node >= NNODES) return;
    int lane = threadIdx.x & 63;
    int beg = rowptr[node], end = rowptr[node + 1];
    const unsigned* inu = (const unsigned*)in;   // 64 uints per row
    float s0 = 0.f, s1 = 0.f;
    int i = beg;
    for (; i + 4 <= end; i += 4) {
        int n0 = srcs[i], n1 = srcs[i + 1], n2 = srcs[i + 2], n3 = srcs[i + 3];
        unsigned v0 = inu[n0 * 64 + lane];
        unsigned v1 = inu[n1 * 64 + lane];
        unsigned v2 = inu[n2 * 64 + lane];
        unsigned v3 = inu[n3 * 64 + lane];
        s0 += __uint_as_float(v0 << 16);
        s1 += __uint_as_float(v0 & 0xFFFF0000u);
        s0 += __uint_as_float(v1 << 16);
        s1 += __uint_as_float(v1 & 0xFFFF0000u);
        s0 += __uint_as_float(v2 << 16);
        s1 += __uint_as_float(v2 & 0xFFFF0000u);
        s0 += __uint_as_float(v3 << 16);
        s1 += __uint_as_float(v3 & 0xFFFF0000u);
    }
    for (; i < end; ++i) {
        unsigned v = inu[srcs[i] * 64 + lane];
        s0 += __uint_as_float(v << 16);
        s1 += __uint_as_float(v & 0xFFFF0000u);
    }
    int cnt = end - beg;
    float inv = (cnt > 0) ? 1.0f / (float)cnt : 0.0f;
    s0 *= inv; s1 *= inv;
    unsigned* agu = (unsigned*)ag;               // 64 uints per row
    agu[node * 64 + lane] = (unsigned)f2bf(s0) | ((unsigned)f2bf(s1) << 16);
}

// ---------------- GEMM: out[i][j] = sum_k Acat[i][k]*W[j][k] + bias[j] ----------------
// Acat = [A0 | A1] (two [M][128] bf16 buffers: aggr and self).
// W: [128][256] bf16. Tile 128x128, K=256 in 4 steps of 64. LDS 32 KiB static.
// EPI 0: relu + bf16 store (layer 1).  EPI 1: f32 store (layer 2).

template <int EPI>
__global__ void __launch_bounds__(256) sage_gemm(const unsigned short* __restrict__ A0,
                                                 const unsigned short* __restrict__ A1,
                                                 const unsigned short* __restrict__ W,
                                                 const float* __restrict__ bias,
                                                 void* __restrict__ outp) {
    __shared__ unsigned short As[128 * 64];
    __shared__ unsigned short Bs[128 * 64];
    const int tid = threadIdx.x;
    const int bm = blockIdx.x * 128;

    f32x4 acc[4][4];
    const f32x4 zero = {0.f, 0.f, 0.f, 0.f};
    for (int m = 0; m < 4; ++m)
        for (int n = 0; n < 4; ++n) acc[m][n] = zero;

    const int lane = tid & 63, wid = tid >> 6;
    const int wr = wid >> 1, wc = wid & 1;
    const int l16 = lane & 15, lhi = lane >> 4;

    for (int kt = 0; kt < 256; kt += 64) {
        const unsigned short* Asrc = (kt < 128) ? A0 : A1;
        const int kofs = kt & 127;
        __syncthreads();  // protect LDS reuse from previous iteration
        #pragma unroll
        for (int it = 0; it < 4; ++it) {
            int idx = it * 2048 + tid * 8;
            int r = idx >> 6, k = idx & 63;
            int row = bm + r; if (row >= NNODES) row = NNODES - 1;
            *(int4*)&As[idx] = *(const int4*)&Asrc[row * 128 + kofs + k];
            *(int4*)&Bs[idx] = *(const int4*)&W[r * 256 + kt + k];
        }
        __syncthreads();
        #pragma unroll
        for (int kk = 0; kk < 64; kk += 32) {
            short8 af[4], bf[4];
            #pragma unroll
            for (int m = 0; m < 4; ++m)
                af[m] = *(const short8*)&As[(wr * 64 + m * 16 + l16) * 64 + kk + lhi * 8];
            #pragma unroll
            for (int n = 0; n < 4; ++n)
                bf[n] = *(const short8*)&Bs[(wc * 64 + n * 16 + l16) * 64 + kk + lhi * 8];
            #pragma unroll
            for (int m = 0; m < 4; ++m)
                #pragma unroll
                for (int n = 0; n < 4; ++n)
                    acc[m][n] = __builtin_amdgcn_mfma_f32_16x16x32_bf16(af[m], bf[n], acc[m][n], 0, 0, 0);
        }
    }

    for (int n = 0; n < 4; ++n) {
        int col = wc * 64 + n * 16 + l16;
        float bv = bias[col];
        for (int m = 0; m < 4; ++m) {
            int row0 = bm + wr * 64 + m * 16 + lhi * 4;
            #pragma unroll
            for (int v = 0; v < 4; ++v) {
                int row = row0 + v;
                if (row < NNODES) {
                    float val = acc[m][n][v] + bv;
                    if (EPI == 0) {
                        val = fmaxf(val, 0.0f);
                        ((unsigned short*)outp)[row * 128 + col] = f2bf(val);
                    } else {
                        ((float*)outp)[row * 128 + col] = val;
                    }
                }
            }
        }
    }
}

// ---------------- row L2 normalize in place (one wave per row) ----------------

__global__ void __launch_bounds__(256) sage_norm(float* __restrict__ out) {
    int node = blockIdx.x * 4 + (threadIdx.x >> 6);
    if (node >= NNODES) return;
    int lane = threadIdx.x & 63;
    float2 v = *(float2*)&out[node * 128 + lane * 2];
    float s = v.x * v.x + v.y * v.y;
    for (int off = 32; off; off >>= 1) s += __shfl_xor(s, off);
    float scale = 1.0f / fmaxf(sqrtf(s), 1e-12f);
    v.x *= scale; v.y *= scale;
    *(float2*)&out[node * 128 + lane * 2] = v;
}

// ---------------- launch ----------------

extern "C" void kernel_launch(void* const* d_in, const int* in_sizes, int n_in,
                              void* d_out, int out_size, void* d_ws, size_t ws_size,
                              hipStream_t stream) {
    const float* x   = (const float*)d_in[0];
    const int* ei    = (const int*)d_in[1];
    const float* W1l = (const float*)d_in[2];
    const float* b1  = (const float*)d_in[3];
    const float* W1r = (const float*)d_in[4];
    const float* W2l = (const float*)d_in[5];
    const float* b2  = (const float*)d_in[6];
    const float* W2r = (const float*)d_in[7];
    const int* srcp = ei;
    const int* dstp = ei + NEDGES;

    char* ws = (char*)d_ws;
    size_t off = 0;
    auto alloc = [&](size_t bytes) -> void* {
        void* p = ws + off;
        off += (bytes + 255) & ~(size_t)255;
        return p;
    };
    int* deg    = (int*)alloc((size_t)NNODES * 4);          // reused as fill
    int* rowptr = (int*)alloc((size_t)(NNODES + 1) * 4);
    int* sorted = (int*)alloc((size_t)NEDGES * 4);
    int* bsum   = (int*)alloc((size_t)SCAN_NB * 4);
    int* bofs   = (int*)alloc((size_t)SCAN_NB * 4);
    unsigned short* xb = (unsigned short*)alloc((size_t)NNODES * DDIM * 2);  // also hb (aliased in time)
    unsigned short* ag = (unsigned short*)alloc((size_t)NNODES * DDIM * 2);
    unsigned short* wc1 = (unsigned short*)alloc(128 * 256 * 2);
    unsigned short* wc2 = (unsigned short*)alloc(128 * 256 * 2);
    unsigned short* hb = xb;  // layer-1 output overwrites xb in place (per-block row ownership)

    // CSR build
    hipMemsetAsync(deg, 0, (size_t)NNODES * 4, stream);
    sage_hist<<<(NEDGES + 255) / 256, 256, 0, stream>>>(dstp, deg);
    sage_scan1<<<SCAN_NB, 256, 0, stream>>>(deg, bsum);
    sage_scan2<<<1, 128, 0, stream>>>(bsum, bofs, rowptr);
    sage_scan3<<<SCAN_NB, 256, 0, stream>>>(deg, bofs, rowptr);
    hipMemsetAsync(deg, 0, (size_t)NNODES * 4, stream);
    sage_scatter<<<(NEDGES + 255) / 256, 256, 0, stream>>>(srcp, dstp, rowptr, deg, sorted);

    // dtype prep
    sage_cvt<<<(NNODES * DDIM / 4 + 255) / 256, 256, 0, stream>>>(x, xb, NNODES * DDIM);
    sage_wprep<<<128, 256, 0, stream>>>(W1l, W1r, wc1);
    sage_wprep<<<128, 256, 0, stream>>>(W2l, W2r, wc2);

    const int aggr_grid = (NNODES + 3) / 4;
    const int gemm_grid = (NNODES + 127) / 128;

    // layer 1: h = relu(aggr@W1l.T + b1 + x@W1r.T)   (bf16, in place over xb)
    sage_aggr<<<aggr_grid, 256, 0, stream>>>(xb, rowptr, sorted, ag);
    sage_gemm<0><<<gemm_grid, 256, 0, stream>>>(ag, xb, wc1, b1, (void*)hb);
    // layer 2: out = aggr@W2l.T + b2 + h@W2r.T       (f32)
    sage_aggr<<<aggr_grid, 256, 0, stream>>>(hb, rowptr, sorted, ag);
    sage_gemm<1><<<gemm_grid, 256, 0, stream>>>(ag, hb, wc2, b2, d_out);
    // normalize rows
    sage_norm<<<aggr_grid, 256, 0, stream>>>((float*)d_out);
}